// Round 11
// baseline (285.588 us; speedup 1.0000x reference)
//
#include <hip/hip_runtime.h>
#include <stdint.h>

typedef unsigned short u16;
typedef unsigned int   u32;
typedef __bf16 bf16;
typedef bf16  bf16x2 __attribute__((ext_vector_type(2)));
typedef bf16  bf16x8 __attribute__((ext_vector_type(8)));
typedef float f32x4  __attribute__((ext_vector_type(4)));

// ---------- helpers ----------

__device__ __forceinline__ u32 pk2(float lo, float hi) {
  bf16x2 t;
  t[0] = (bf16)lo;
  t[1] = (bf16)hi;
  return __builtin_bit_cast(u32, t);
}

__device__ __forceinline__ u16 b1(float f) {
  bf16 t = (bf16)f;
  return __builtin_bit_cast(u16, t);
}

// ---------- fp32 -> bf16 conversion (activations + weights) ----------

__global__ __launch_bounds__(256) void cvt_all(
    const float* q, const float* k, const float* v,
    const float* wq, const float* wk, const float* wv, const float* wo,
    u16* qb, u16* kb, u16* vb,
    u16* wqb, u16* wkb, u16* wvb, u16* wob)
{
  const float* src; u16* dst; int n4;
  switch (blockIdx.y) {
    case 0: src = q;  dst = qb;  n4 = 1048576; break;
    case 1: src = k;  dst = kb;  n4 = 1048576; break;
    case 2: src = v;  dst = vb;  n4 = 1048576; break;
    case 3: src = wq; dst = wqb; n4 = 262144;  break;
    case 4: src = wk; dst = wkb; n4 = 262144;  break;
    case 5: src = wv; dst = wvb; n4 = 262144;  break;
    default: src = wo; dst = wob; n4 = 262144; break;
  }
  int stride = gridDim.x * blockDim.x;
  for (int i = blockIdx.x * blockDim.x + threadIdx.x; i < n4; i += stride) {
    float4 f = ((const float4*)src)[i];
    uint2 o;
    o.x = pk2(f.x, f.y);
    o.y = pk2(f.z, f.w);
    ((uint2*)dst)[i] = o;
  }
}

// ---------- no-LDS register GEMM core ----------
// C[128x128] tile, 4 waves (wr,wc in 2x2), fragments loaded DIRECTLY from
// global (L2-resident panels). Lane (r16,g): af[m] row = wr*64+m*16+r16,
// k = kt*64+ks*32+g*8 (8 contiguous bf16 = 16B; lanes {x,x+16,x+32,x+48}
// cover one full 64B line -> full-line coalesced). No LDS, no barriers.

__device__ __forceinline__ void gemm_core_reg(
    const u16* Abase, const u16* Wbase, f32x4 acc[4][4])
{
  for (int kt = 0; kt < 16; ++kt) {
    int ko = kt * 64;
    bf16x8 af[4][2], bw[4][2];
    #pragma unroll
    for (int m = 0; m < 4; ++m) {
      #pragma unroll
      for (int ks = 0; ks < 2; ++ks) {
        af[m][ks] = *(const bf16x8*)(Abase + m * 16384 + ko + ks * 32);
        bw[m][ks] = *(const bf16x8*)(Wbase + m * 16384 + ko + ks * 32);
      }
    }
    #pragma unroll
    for (int ks = 0; ks < 2; ++ks)
      #pragma unroll
      for (int m = 0; m < 4; ++m)
        #pragma unroll
        for (int n = 0; n < 4; ++n)
          acc[m][n] = __builtin_amdgcn_mfma_f32_16x16x32_bf16(
              af[m][ks], bw[n][ks], acc[m][n], 0, 0, 0);
  }
}

// ---------- QKV projection (z=0:Q, 1:K, 2:V) ----------
// Q,K out: [B,H,T,D]  V out: [B,H,D,T]

__global__ __launch_bounds__(256) void proj_gemm(
    const u16* qb, const u16* kb, const u16* vb,
    const u16* wqb, const u16* wkb, const u16* wvb,
    const float* bq, const float* bk, const float* bv,
    u16* qh, u16* kh, u16* vt)
{
  int tid = threadIdx.x, lane = tid & 63;
  int g = lane >> 4, r16 = lane & 15;
  int bi = blockIdx.x & 31, bj = blockIdx.x >> 5;   // 32 x 8
  int z = blockIdx.z;
  const u16* A = (z == 0) ? qb : (z == 1) ? kb : vb;
  const u16* W = (z == 0) ? wqb : (z == 1) ? wkb : wvb;
  const float* bias = (z == 0) ? bq : (z == 1) ? bk : bv;
  u16* dst = (z == 0) ? qh : (z == 1) ? kh : vt;

  int wr = (tid >> 7) & 1, wc = (tid >> 6) & 1;
  const u16* Abase = A + (bi * 128 + wr * 64 + r16) * 1024 + g * 8;
  const u16* Wbase = W + (bj * 128 + wc * 64 + r16) * 1024 + g * 8;

  f32x4 acc[4][4] = {};
  gemm_core_reg(Abase, Wbase, acc);

  int rbase = bi * 128 + wr * 64 + (g << 2);
  int cbase = bj * 128 + wc * 64;
  #pragma unroll
  for (int n = 0; n < 4; ++n) {
    int col = cbase + n * 16 + r16;
    float bsv = bias[col];
    int h = col >> 6, d = col & 63;
    #pragma unroll
    for (int m = 0; m < 4; ++m) {
      #pragma unroll
      for (int r = 0; r < 4; ++r) {
        int R = rbase + m * 16 + r;
        int b = R >> 10, t = R & 1023;
        u16 val = b1(acc[m][n][r] + bsv);
        if (z < 2) dst[(((b * 16 + h) * 1024 + t) << 6) + d] = val;
        else       dst[(((b * 16 + h) * 64 + d) << 10) + t] = val;
      }
    }
  }
}

// ---------- output projection: attn @ Wo^T + bo -> fp32 d_out ----------

__global__ __launch_bounds__(256) void out_gemm(
    const u16* attn, const u16* wob, const float* bo, float* out)
{
  int tid = threadIdx.x, lane = tid & 63;
  int g = lane >> 4, r16 = lane & 15;
  int bi = blockIdx.x & 31, bj = blockIdx.x >> 5;

  int wr = (tid >> 7) & 1, wc = (tid >> 6) & 1;
  const u16* Abase = attn + (bi * 128 + wr * 64 + r16) * 1024 + g * 8;
  const u16* Wbase = wob + (bj * 128 + wc * 64 + r16) * 1024 + g * 8;

  f32x4 acc[4][4] = {};
  gemm_core_reg(Abase, Wbase, acc);

  int rbase = bi * 128 + wr * 64 + (g << 2);
  int cbase = bj * 128 + wc * 64;
  #pragma unroll
  for (int n = 0; n < 4; ++n) {
    int col = cbase + n * 16 + r16;
    float bsv = bo[col];
    #pragma unroll
    for (int m = 0; m < 4; ++m) {
      #pragma unroll
      for (int r = 0; r < 4; ++r) {
        int R = rbase + m * 16 + r;
        out[R * 1024 + col] = acc[m][n][r] + bsv;
      }
    }
  }
}

// ---------- flash attention (unchanged from round 10) ----------

__global__ __launch_bounds__(256, 2) void attn_fwd(
    const u16* qh, const u16* kh, const u16* vt, u16* attnb)
{
  __shared__ alignas(16) u16 Ks[64 * 72];
  __shared__ alignas(16) u16 Vs[64 * 72];
  __shared__ alignas(16) u16 Pl[4][16 * 72];

  const float SC = 0.125f;
  const float RTHR = 64.0f;

  int tid = threadIdx.x, lane = tid & 63, w = tid >> 6;
  int g = lane >> 4;
  int q0 = blockIdx.x << 6;
  int bh = blockIdx.y;
  const u16* qbase = qh + bh * 65536;   // [t][d]
  const u16* kbase = kh + bh * 65536;   // [t][d]
  const u16* vbase = vt + bh * 65536;   // [d][t]

  bf16x8 qf[2];
  {
    int qrow = q0 + w * 16 + (lane & 15);
    const u16* p = qbase + qrow * 64 + (g << 3);
    qf[0] = *(const bf16x8*)p;
    qf[1] = *(const bf16x8*)(p + 32);
  }

  f32x4 ot[4] = {};
  float m_r = -3.0e38f, l_r = 0.f;

  int sr = tid >> 2;
  int sj = (tid & 3) << 4;
  u16* pw = Pl[w];
  int prow = (lane & 15) * 72;

  const u16* ksrc0 = kbase + sr * 64 + sj;
  const u16* vsrc0 = vbase + sr * 1024 + sj;

  bf16x8 kr0, kr1, vr0, vr1;
  kr0 = *(const bf16x8*)(ksrc0);
  kr1 = *(const bf16x8*)(ksrc0 + 8);
  vr0 = *(const bf16x8*)(vsrc0);
  vr1 = *(const bf16x8*)(vsrc0 + 8);

  for (int kv0 = 0; kv0 < 1024; kv0 += 64) {
    *(bf16x8*)(Ks + sr * 72 + sj)     = kr0;
    *(bf16x8*)(Ks + sr * 72 + sj + 8) = kr1;
    *(bf16x8*)(Vs + sr * 72 + sj)     = vr0;
    *(bf16x8*)(Vs + sr * 72 + sj + 8) = vr1;
    __syncthreads();

    if (kv0 < 960) {
      const u16* kn = ksrc0 + (kv0 + 64) * 64;
      const u16* vn = vsrc0 + (kv0 + 64);
      kr0 = *(const bf16x8*)(kn);
      kr1 = *(const bf16x8*)(kn + 8);
      vr0 = *(const bf16x8*)(vn);
      vr1 = *(const bf16x8*)(vn + 8);
    }

    // S^T = K * Q^T (raw scores)
    f32x4 sc[4] = {};
    #pragma unroll
    for (int ks = 0; ks < 2; ++ks) {
      #pragma unroll
      for (int m = 0; m < 4; ++m) {
        bf16x8 kf = *(const bf16x8*)(Ks + (m * 16 + (lane & 15)) * 72 + ks * 32 + g * 8);
        sc[m] = __builtin_amdgcn_mfma_f32_16x16x32_bf16(kf, qf[ks], sc[m], 0, 0, 0);
      }
    }

    float vmax = -3.0e38f;
    #pragma unroll
    for (int m = 0; m < 4; ++m)
      #pragma unroll
      for (int r = 0; r < 4; ++r)
        vmax = fmaxf(vmax, sc[m][r]);
    vmax = fmaxf(vmax, __shfl_xor(vmax, 16, 64));
    vmax = fmaxf(vmax, __shfl_xor(vmax, 32, 64));

    if (!__all(vmax - m_r <= RTHR)) {    // T13 defer-max
      float mnew = fmaxf(m_r, vmax);
      float fac = __expf((m_r - mnew) * SC);
      l_r *= fac;
      #pragma unroll
      for (int dm = 0; dm < 4; ++dm) ot[dm] *= fac;
      m_r = mnew;
    }
    float nm = -m_r * SC;

    float psum = 0.f;
    u32 pp[4][2];
    #pragma unroll
    for (int m = 0; m < 4; ++m) {
      float p0 = __expf(fmaf(sc[m][0], SC, nm));
      float p1 = __expf(fmaf(sc[m][1], SC, nm));
      float p2 = __expf(fmaf(sc[m][2], SC, nm));
      float p3 = __expf(fmaf(sc[m][3], SC, nm));
      psum += (p0 + p1) + (p2 + p3);
      pp[m][0] = pk2(p0, p1);
      pp[m][1] = pk2(p2, p3);
    }
    psum += __shfl_xor(psum, 16, 64);
    psum += __shfl_xor(psum, 32, 64);
    l_r += psum;

    #pragma unroll
    for (int m = 0; m < 4; ++m) {
      u32* d = (u32*)(pw + prow + m * 16 + (g << 2));
      d[0] = pp[m][0];
      d[1] = pp[m][1];
    }

    // O^T += V^T * P^T
    #pragma unroll
    for (int ks = 0; ks < 2; ++ks) {
      bf16x8 pf = *(const bf16x8*)(pw + prow + ks * 32 + g * 8);
      #pragma unroll
      for (int dm = 0; dm < 4; ++dm) {
        bf16x8 vf = *(const bf16x8*)(Vs + (dm * 16 + (lane & 15)) * 72 + ks * 32 + g * 8);
        ot[dm] = __builtin_amdgcn_mfma_f32_16x16x32_bf16(vf, pf, ot[dm], 0, 0, 0);
      }
    }
    __syncthreads();
  }

  float inv = 1.0f / l_r;
  int b = bh >> 4, h = bh & 15;
  int tok = (b << 10) + q0 + w * 16 + (lane & 15);
  u16* obase = attnb + tok * 1024 + h * 64;
  #pragma unroll
  for (int dm = 0; dm < 4; ++dm) {
    int d0 = dm * 16 + (g << 2);
    u32* d = (u32*)(obase + d0);
    d[0] = pk2(ot[dm][0] * inv, ot[dm][1] * inv);
    d[1] = pk2(ot[dm][2] * inv, ot[dm][3] * inv);
  }
}

// ---------- launch ----------

extern "C" void kernel_launch(void* const* d_in, const int* in_sizes, int n_in,
                              void* d_out, int out_size, void* d_ws, size_t ws_size,
                              hipStream_t stream)
{
  const float* q  = (const float*)d_in[0];
  const float* k  = (const float*)d_in[1];
  const float* v  = (const float*)d_in[2];
  const float* Wq = (const float*)d_in[3];
  const float* bq = (const float*)d_in[4];
  const float* Wk = (const float*)d_in[5];
  const float* bk = (const float*)d_in[6];
  const float* Wv = (const float*)d_in[7];
  const float* bv = (const float*)d_in[8];
  const float* Wo = (const float*)d_in[9];
  const float* bo = (const float*)d_in[10];
  float* out = (float*)d_out;

  u16* ws  = (u16*)d_ws;
  u16* qb  = ws;                    // 4M elems each (bf16)
  u16* kb  = qb  + (4u << 20);
  u16* vb  = kb  + (4u << 20);
  u16* wqb = vb  + (4u << 20);      // 1M each
  u16* wkb = wqb + (1u << 20);
  u16* wvb = wkb + (1u << 20);
  u16* wob = wvb + (1u << 20);
  u16* qhb = wob + (1u << 20);      // 4M each
  u16* khb = qhb + (4u << 20);
  u16* vtb = khb + (4u << 20);
  u16* atb = vtb + (4u << 20);      // total 64 MiB

  cvt_all<<<dim3(1024, 7, 1), 256, 0, stream>>>(q, k, v, Wq, Wk, Wv, Wo,
                                                qb, kb, vb, wqb, wkb, wvb, wob);
  proj_gemm<<<dim3(256, 1, 3), 256, 0, stream>>>(qb, kb, vb, wqb, wkb, wvb,
                                                 bq, bk, bv, qhb, khb, vtb);
  attn_fwd<<<dim3(16, 64, 1), 256, 0, stream>>>(qhb, khb, vtb, atb);
  out_gemm<<<dim3(256, 1, 1), 256, 0, stream>>>(atb, wob, bo, out);
}

// Round 12
// 208.583 us; speedup vs baseline: 1.3692x; 1.3692x over previous
//
#include <hip/hip_runtime.h>
#include <stdint.h>

typedef unsigned short u16;
typedef unsigned int   u32;
typedef __bf16 bf16;
typedef bf16  bf16x2 __attribute__((ext_vector_type(2)));
typedef bf16  bf16x8 __attribute__((ext_vector_type(8)));
typedef float f32x4  __attribute__((ext_vector_type(4)));

#define AS1 __attribute__((address_space(1)))
#define AS3 __attribute__((address_space(3)))

// ---------- helpers ----------

__device__ __forceinline__ u32 pk2(float lo, float hi) {
  bf16x2 t;
  t[0] = (bf16)lo;
  t[1] = (bf16)hi;
  return __builtin_bit_cast(u32, t);
}

__device__ __forceinline__ u16 b1(float f) {
  bf16 t = (bf16)f;
  return __builtin_bit_cast(u16, t);
}

__device__ __forceinline__ void gload_lds16(const void* src, void* dst) {
  // 16B per lane, HW dest = wave-uniform base + lane*16
  __builtin_amdgcn_global_load_lds((const AS1 void*)src, (AS3 void*)dst, 16, 0, 0);
}

// swizzled fragment read from a [rows][128B] LDS tile: byte ^= (row&7)<<4
__device__ __forceinline__ bf16x8 fragS(const char* lds, int row, int kbyte) {
  return *(const bf16x8*)(lds + row * 128 + (kbyte ^ ((row & 7) << 4)));
}

// ---------- fp32 -> bf16 conversion (activations + weights) ----------

__global__ __launch_bounds__(256) void cvt_all(
    const float* q, const float* k, const float* v,
    const float* wq, const float* wk, const float* wv, const float* wo,
    u16* qb, u16* kb, u16* vb,
    u16* wqb, u16* wkb, u16* wvb, u16* wob)
{
  const float* src; u16* dst; int n4;
  switch (blockIdx.y) {
    case 0: src = q;  dst = qb;  n4 = 1048576; break;
    case 1: src = k;  dst = kb;  n4 = 1048576; break;
    case 2: src = v;  dst = vb;  n4 = 1048576; break;
    case 3: src = wq; dst = wqb; n4 = 262144;  break;
    case 4: src = wk; dst = wkb; n4 = 262144;  break;
    case 5: src = wv; dst = wvb; n4 = 262144;  break;
    default: src = wo; dst = wob; n4 = 262144; break;
  }
  int stride = gridDim.x * blockDim.x;
  for (int i = blockIdx.x * blockDim.x + threadIdx.x; i < n4; i += stride) {
    float4 f = ((const float4*)src)[i];
    uint2 o;
    o.x = pk2(f.x, f.y);
    o.y = pk2(f.z, f.w);
    ((uint2*)dst)[i] = o;
  }
}

// ---------- GEMM core: C[128x128] = A[128xK] * W[128xK]^T, K=1024 ----------
// m97 structure (round-3, proj <= 49.7us) + both-sides XOR swizzle
// (round-7-proven: conflicts 9.4M -> 0, absmax-identical).
// LDS [128][64] bf16 per operand; staging via global_load_lds with
// pre-swizzled global source (linear LDS dest), reads via fragS.

__device__ __forceinline__ void stageSw128(const u16* gtile, char* lds, int tid)
{
  int w = tid >> 6, lane = tid & 63;
  int rr = lane >> 3;                        // row within 8-row chunk == row&7
  int cb = (lane & 7) << 4;                  // byte col within 128B row
  #pragma unroll
  for (int i = 0; i < 4; ++i) {
    int c = i * 4 + w;                       // chunk 0..15, 1KB each (8 rows)
    int r = c * 8 + rr;
    gload_lds16((const char*)(gtile + r * 1024) + (cb ^ (rr << 4)), lds + c * 1024);
  }
}

__device__ __forceinline__ void gemm_core(const u16* A, const u16* W,
                                          f32x4 acc[4][4], int bi, int bj,
                                          int tid, char* As, char* Bs)
{
  int lane = tid & 63;
  int wr = (tid >> 7) & 1, wc = (tid >> 6) & 1;
  for (int kt = 0; kt < 16; ++kt) {
    stageSw128(A + bi * 131072 + kt * 64, As, tid);
    stageSw128(W + bj * 131072 + kt * 64, Bs, tid);
    __syncthreads();
    #pragma unroll
    for (int ks = 0; ks < 2; ++ks) {
      int kb = ks * 64 + ((lane >> 4) << 4);
      bf16x8 af[4], bfr[4];
      #pragma unroll
      for (int m = 0; m < 4; ++m) af[m]  = fragS(As, wr * 64 + m * 16 + (lane & 15), kb);
      #pragma unroll
      for (int n = 0; n < 4; ++n) bfr[n] = fragS(Bs, wc * 64 + n * 16 + (lane & 15), kb);
      #pragma unroll
      for (int m = 0; m < 4; ++m)
        #pragma unroll
        for (int n = 0; n < 4; ++n)
          acc[m][n] = __builtin_amdgcn_mfma_f32_16x16x32_bf16(af[m], bfr[n], acc[m][n], 0, 0, 0);
    }
    __syncthreads();
  }
}

// ---------- QKV projection (z=0:Q, 1:K, 2:V) ----------
// Q,K out: [B,H,T,D]  V out: [B,H,D,T]

__global__ __launch_bounds__(256, 2) void proj_gemm(
    const u16* qb, const u16* kb, const u16* vb,
    const u16* wqb, const u16* wkb, const u16* wvb,
    const float* bq, const float* bk, const float* bv,
    u16* qh, u16* kh, u16* vt)
{
  __shared__ alignas(16) char As[16384];
  __shared__ alignas(16) char Bs[16384];
  int tid = threadIdx.x;
  int bi = blockIdx.x & 31, bj = blockIdx.x >> 5;
  int z = blockIdx.z;
  const u16* A = (z == 0) ? qb : (z == 1) ? kb : vb;
  const u16* W = (z == 0) ? wqb : (z == 1) ? wkb : wvb;
  const float* bias = (z == 0) ? bq : (z == 1) ? bk : bv;
  u16* dst = (z == 0) ? qh : (z == 1) ? kh : vt;

  f32x4 acc[4][4] = {};
  gemm_core(A, W, acc, bi, bj, tid, As, Bs);

  int lane = tid & 63, wr = (tid >> 7) & 1, wc = (tid >> 6) & 1;
  int rbase = bi * 128 + wr * 64 + ((lane >> 4) << 2);
  int cbase = bj * 128 + wc * 64;
  #pragma unroll
  for (int n = 0; n < 4; ++n) {
    int col = cbase + n * 16 + (lane & 15);
    float bsv = bias[col];
    int h = col >> 6, d = col & 63;
    #pragma unroll
    for (int m = 0; m < 4; ++m) {
      #pragma unroll
      for (int r = 0; r < 4; ++r) {
        int R = rbase + m * 16 + r;
        int b = R >> 10, t = R & 1023;
        u16 val = b1(acc[m][n][r] + bsv);
        if (z < 2) dst[(((b * 16 + h) * 1024 + t) << 6) + d] = val;
        else       dst[(((b * 16 + h) * 64 + d) << 10) + t] = val;
      }
    }
  }
}

// ---------- output projection: attn[4096x1024] @ Wo^T + bo -> FP32 d_out ----

__global__ __launch_bounds__(256, 2) void out_gemm(
    const u16* attn, const u16* wob, const float* bo, float* out)
{
  __shared__ alignas(16) char As[16384];
  __shared__ alignas(16) char Bs[16384];
  int tid = threadIdx.x;
  int bi = blockIdx.x & 31, bj = blockIdx.x >> 5;

  f32x4 acc[4][4] = {};
  gemm_core(attn, wob, acc, bi, bj, tid, As, Bs);

  int lane = tid & 63, wr = (tid >> 7) & 1, wc = (tid >> 6) & 1;
  int rbase = bi * 128 + wr * 64 + ((lane >> 4) << 2);
  int cbase = bj * 128 + wc * 64;
  #pragma unroll
  for (int n = 0; n < 4; ++n) {
    int col = cbase + n * 16 + (lane & 15);
    float bsv = bo[col];
    #pragma unroll
    for (int m = 0; m < 4; ++m) {
      #pragma unroll
      for (int r = 0; r < 4; ++r) {
        int R = rbase + m * 16 + r;
        out[R * 1024 + col] = acc[m][n][r] + bsv;   // fp32 output
      }
    }
  }
}

// ---------- flash attention (round-10 version, unchanged) ----------

__global__ __launch_bounds__(256, 2) void attn_fwd(
    const u16* qh, const u16* kh, const u16* vt, u16* attnb)
{
  __shared__ alignas(16) u16 Ks[64 * 72];
  __shared__ alignas(16) u16 Vs[64 * 72];
  __shared__ alignas(16) u16 Pl[4][16 * 72];

  const float SC = 0.125f;
  const float RTHR = 64.0f;

  int tid = threadIdx.x, lane = tid & 63, w = tid >> 6;
  int g = lane >> 4;
  int q0 = blockIdx.x << 6;
  int bh = blockIdx.y;
  const u16* qbase = qh + bh * 65536;   // [t][d]
  const u16* kbase = kh + bh * 65536;   // [t][d]
  const u16* vbase = vt + bh * 65536;   // [d][t]

  bf16x8 qf[2];
  {
    int qrow = q0 + w * 16 + (lane & 15);
    const u16* p = qbase + qrow * 64 + (g << 3);
    qf[0] = *(const bf16x8*)p;
    qf[1] = *(const bf16x8*)(p + 32);
  }

  f32x4 ot[4] = {};
  float m_r = -3.0e38f, l_r = 0.f;

  int sr = tid >> 2;
  int sj = (tid & 3) << 4;
  u16* pw = Pl[w];
  int prow = (lane & 15) * 72;

  const u16* ksrc0 = kbase + sr * 64 + sj;
  const u16* vsrc0 = vbase + sr * 1024 + sj;

  bf16x8 kr0, kr1, vr0, vr1;
  kr0 = *(const bf16x8*)(ksrc0);
  kr1 = *(const bf16x8*)(ksrc0 + 8);
  vr0 = *(const bf16x8*)(vsrc0);
  vr1 = *(const bf16x8*)(vsrc0 + 8);

  for (int kv0 = 0; kv0 < 1024; kv0 += 64) {
    *(bf16x8*)(Ks + sr * 72 + sj)     = kr0;
    *(bf16x8*)(Ks + sr * 72 + sj + 8) = kr1;
    *(bf16x8*)(Vs + sr * 72 + sj)     = vr0;
    *(bf16x8*)(Vs + sr * 72 + sj + 8) = vr1;
    __syncthreads();

    if (kv0 < 960) {
      const u16* kn = ksrc0 + (kv0 + 64) * 64;
      const u16* vn = vsrc0 + (kv0 + 64);
      kr0 = *(const bf16x8*)(kn);
      kr1 = *(const bf16x8*)(kn + 8);
      vr0 = *(const bf16x8*)(vn);
      vr1 = *(const bf16x8*)(vn + 8);
    }

    // S^T = K * Q^T (raw scores)
    f32x4 sc[4] = {};
    #pragma unroll
    for (int ks = 0; ks < 2; ++ks) {
      #pragma unroll
      for (int m = 0; m < 4; ++m) {
        bf16x8 kf = *(const bf16x8*)(Ks + (m * 16 + (lane & 15)) * 72 + ks * 32 + g * 8);
        sc[m] = __builtin_amdgcn_mfma_f32_16x16x32_bf16(kf, qf[ks], sc[m], 0, 0, 0);
      }
    }

    float vmax = -3.0e38f;
    #pragma unroll
    for (int m = 0; m < 4; ++m)
      #pragma unroll
      for (int r = 0; r < 4; ++r)
        vmax = fmaxf(vmax, sc[m][r]);
    vmax = fmaxf(vmax, __shfl_xor(vmax, 16, 64));
    vmax = fmaxf(vmax, __shfl_xor(vmax, 32, 64));

    if (!__all(vmax - m_r <= RTHR)) {    // T13 defer-max
      float mnew = fmaxf(m_r, vmax);
      float fac = __expf((m_r - mnew) * SC);
      l_r *= fac;
      #pragma unroll
      for (int dm = 0; dm < 4; ++dm) ot[dm] *= fac;
      m_r = mnew;
    }
    float nm = -m_r * SC;

    float psum = 0.f;
    u32 pp[4][2];
    #pragma unroll
    for (int m = 0; m < 4; ++m) {
      float p0 = __expf(fmaf(sc[m][0], SC, nm));
      float p1 = __expf(fmaf(sc[m][1], SC, nm));
      float p2 = __expf(fmaf(sc[m][2], SC, nm));
      float p3 = __expf(fmaf(sc[m][3], SC, nm));
      psum += (p0 + p1) + (p2 + p3);
      pp[m][0] = pk2(p0, p1);
      pp[m][1] = pk2(p2, p3);
    }
    psum += __shfl_xor(psum, 16, 64);
    psum += __shfl_xor(psum, 32, 64);
    l_r += psum;

    #pragma unroll
    for (int m = 0; m < 4; ++m) {
      u32* d = (u32*)(pw + prow + m * 16 + (g << 2));
      d[0] = pp[m][0];
      d[1] = pp[m][1];
    }

    // O^T += V^T * P^T
    #pragma unroll
    for (int ks = 0; ks < 2; ++ks) {
      bf16x8 pf = *(const bf16x8*)(pw + prow + ks * 32 + g * 8);
      #pragma unroll
      for (int dm = 0; dm < 4; ++dm) {
        bf16x8 vf = *(const bf16x8*)(Vs + (dm * 16 + (lane & 15)) * 72 + ks * 32 + g * 8);
        ot[dm] = __builtin_amdgcn_mfma_f32_16x16x32_bf16(vf, pf, ot[dm], 0, 0, 0);
      }
    }
    __syncthreads();
  }

  float inv = 1.0f / l_r;
  int b = bh >> 4, h = bh & 15;
  int tok = (b << 10) + q0 + w * 16 + (lane & 15);
  u16* obase = attnb + tok * 1024 + h * 64;
  #pragma unroll
  for (int dm = 0; dm < 4; ++dm) {
    int d0 = dm * 16 + (g << 2);
    u32* d = (u32*)(obase + d0);
    d[0] = pk2(ot[dm][0] * inv, ot[dm][1] * inv);
    d[1] = pk2(ot[dm][2] * inv, ot[dm][3] * inv);
  }
}

// ---------- launch ----------

extern "C" void kernel_launch(void* const* d_in, const int* in_sizes, int n_in,
                              void* d_out, int out_size, void* d_ws, size_t ws_size,
                              hipStream_t stream)
{
  const float* q  = (const float*)d_in[0];
  const float* k  = (const float*)d_in[1];
  const float* v  = (const float*)d_in[2];
  const float* Wq = (const float*)d_in[3];
  const float* bq = (const float*)d_in[4];
  const float* Wk = (const float*)d_in[5];
  const float* bk = (const float*)d_in[6];
  const float* Wv = (const float*)d_in[7];
  const float* bv = (const float*)d_in[8];
  const float* Wo = (const float*)d_in[9];
  const float* bo = (const float*)d_in[10];
  float* out = (float*)d_out;

  u16* ws  = (u16*)d_ws;
  u16* qb  = ws;                    // 4M elems each (bf16)
  u16* kb  = qb  + (4u << 20);
  u16* vb  = kb  + (4u << 20);
  u16* wqb = vb  + (4u << 20);      // 1M each
  u16* wkb = wqb + (1u << 20);
  u16* wvb = wkb + (1u << 20);
  u16* wob = wvb + (1u << 20);
  u16* qhb = wob + (1u << 20);      // 4M each
  u16* khb = qhb + (4u << 20);
  u16* vtb = khb + (4u << 20);
  u16* atb = vtb + (4u << 20);      // total 64 MiB

  cvt_all<<<dim3(1024, 7, 1), 256, 0, stream>>>(q, k, v, Wq, Wk, Wv, Wo,
                                                qb, kb, vb, wqb, wkb, wvb, wob);
  proj_gemm<<<dim3(256, 1, 3), 256, 0, stream>>>(qb, kb, vb, wqb, wkb, wvb,
                                                 bq, bk, bv, qhb, khb, vtb);
  attn_fwd<<<dim3(16, 64, 1), 256, 0, stream>>>(qhb, khb, vtb, atb);
  out_gemm<<<dim3(256, 1, 1), 256, 0, stream>>>(atb, wob, bo, out);
}